// Round 15
// baseline (72.344 us; speedup 1.0000x reference)
//
#include <hip/hip_runtime.h>
#include <math.h>

// ---------------------------------------------------------------------------
// ZBL repulsion, R15: R13 skeleton + fire-and-forget LDS atomic deposits
// (segmented shuffle reduction DELETED — it was ~500 serial cy/wave-iter).
//  - 1024-thr persistent blocks (256 = 1/CU), LDS z8 (100 KB) + za[256]
//  - depth-3 / unroll-2 register pipeline, barrier-free main loop
//  - each thread: atomicAdd(&s_acc[key - kbase], rep)  [no return -> no
//    wave stall; same-address serialization is LDS-pipe time only]
//  - CAP=2048 slots, global-atomic fallback keeps any input correct
//  - flush slots to global after loop; separate epilogue kernel (R13 style)
//  - native exp2/rcp/rsq lean math (validated absmax 2.4e-4)
// ---------------------------------------------------------------------------

#define LOG2E 1.4426950408889634f
#define BLK   1024
#define NBLK  256
#define STRD  (2 * BLK)
#define CAP   2048

static __device__ __forceinline__ float rcpf_(float x)  { return __builtin_amdgcn_rcpf(x); }
static __device__ __forceinline__ float rsqf_(float x)  { return __builtin_amdgcn_rsqf(x); }
static __device__ __forceinline__ float exp2f_(float x) { return __builtin_amdgcn_exp2f(x); }
static __device__ __forceinline__ float log2f_(float x) { return __builtin_amdgcn_logf(x); }

struct f3 { float x, y, z; };
struct G  { int ii, jj; float bm, dx, dy, dz; };

__global__ void zbl_k0(const float* __restrict__ an,
                       unsigned char* __restrict__ z8,
                       float* __restrict__ out, int n) {
    int i = blockIdx.x * blockDim.x + threadIdx.x;
    if (i >= n) return;
    int z = (int)(an[i] + 0.5f);
    z8[i] = (unsigned char)min(max(z, 1), 255);
    out[i] = 0.0f;                       // d_out zeroing folded in
}

static __device__ __forceinline__ G loadG(const int* __restrict__ idx_i,
                                          const int* __restrict__ idx_j,
                                          const float* __restrict__ bmk,
                                          const float* __restrict__ disp,
                                          int p, int cend) {
    G g; g.ii = -1; g.jj = 0; g.bm = 0.0f; g.dx = 0.0f; g.dy = 0.0f; g.dz = 0.0f;
    if (p < cend) {
        g.ii = idx_i[p];
        g.jj = idx_j[p];
        g.bm = bmk[p];
        f3 d = *reinterpret_cast<const f3*>(disp + (long)p * 3);
        g.dx = d.x; g.dy = d.y; g.dz = d.z;
    }
    return g;
}

__global__ __launch_bounds__(BLK) void zbl_pair_kernel(
    const float* __restrict__ disp,
    const int*   __restrict__ idx_i,       // sorted
    const int*   __restrict__ idx_j,
    const float* __restrict__ batch_mask,
    const unsigned char* __restrict__ z8g,
    const float* __restrict__ a_coef_ptr,
    const float* __restrict__ a_exp_ptr,
    const float* __restrict__ phi_c,
    const float* __restrict__ phi_e,
    float* __restrict__ out_acc,           // [N] zeroed accumulator
    int nA, int nP)
{
    extern __shared__ unsigned char smem[];
    const int nA_pad = (nA + 15) & ~15;
    unsigned char* s_z8  = smem;                                // nA_pad B
    float*         s_za  = (float*)(smem + nA_pad);             // 256 f
    float*         s_acc = (float*)(smem + nA_pad + 1024);      // CAP f

    const int tid = threadIdx.x;

    // one-time: z8 table (coalesced uint4) + za table + zero slot acc
    {
        const int nw = nA >> 4;
        const uint4* g4 = reinterpret_cast<const uint4*>(z8g);
        uint4* s4 = reinterpret_cast<uint4*>(s_z8);
        for (int i = tid; i < nw; i += BLK) s4[i] = g4[i];
        for (int i = (nw << 4) + tid; i < nA; i += BLK) s_z8[i] = z8g[i];
    }
    if (tid < 256) {
        float ae = fabsf(a_exp_ptr[0]);
        int z = max(tid, 1);
        s_za[tid] = exp2f_(ae * log2f_((float)z));   // z^|ae|
    }
    for (int i = tid; i < CAP; i += BLK) s_acc[i] = 0.0f;

    // per-thread uniforms
    const float ac_inv = rcpf_(fmaxf(fabsf(a_coef_ptr[0]), 1e-10f));
    float c0 = fabsf(phi_c[0]), c1 = fabsf(phi_c[1]);
    float c2 = fabsf(phi_c[2]), c3 = fabsf(phi_c[3]);
    const float cinv = rcpf_(fmaxf(c0 + c1 + c2 + c3, 1e-10f));
    c0 *= cinv; c1 *= cinv; c2 *= cinv; c3 *= cinv;
    const float e0 = fmaxf(fabsf(phi_e[0]), 1e-10f);
    const float e1 = fmaxf(fabsf(phi_e[1]), 1e-10f);
    const float e2 = fmaxf(fabsf(phi_e[2]), 1e-10f);
    const float e3 = fmaxf(fabsf(phi_e[3]), 1e-10f);

    int chunk = (nP + NBLK - 1) / NBLK;
    chunk = (chunk + STRD - 1) & ~(STRD - 1);
    const int cbeg = blockIdx.x * chunk;
    const int cend = min(cbeg + chunk, nP);
    const int kbase = (cbeg < nP) ? idx_i[cbeg] : 0;

    __syncthreads();   // tables + slot acc ready

#define COMPUTE_G(g, rep, key)                                                  \
    {                                                                           \
        rep = 0.0f; key = -1;                                                   \
        if ((g).ii >= 0) {                                                      \
            const int zi = (int)s_z8[(g).ii];                                   \
            const int zj = (int)s_z8[(g).jj];                                   \
            const float za_i = s_za[zi];                                        \
            const float za_j = s_za[zj];                                        \
            const float add = 1.0f - (g).bm;                                    \
            const float dx = (g).dx + add, dy = (g).dy + add, dz = (g).dz + add;\
            float d2   = fmaxf(dx * dx + dy * dy + dz * dz, 1e-20f);            \
            float rsq  = rsqf_(d2);                                             \
            float dist = d2 * rsq;                                              \
            float tt = dist * 0.1f;                                             \
            float tc = fminf(fmaxf(tt, 1e-9f), 1.0f - 1e-9f);                   \
            float u  = (1.0f - 2.0f * tc) * rcpf_(tc - tc * tc);                \
            float s  = rcpf_(1.0f + exp2f_(u * LOG2E));                         \
            float sw = (tt >= 1.0f) ? 1.0f : s;                                 \
            float za_sum = za_i + za_j;                                         \
            float arg  = fminf(dist * za_sum * ac_inv, 1e6f);                   \
            float narg = -arg * LOG2E;                                          \
            float phi  = c0 * exp2f_(e0 * narg) + c1 * exp2f_(e1 * narg) +      \
                         c2 * exp2f_(e2 * narg) + c3 * exp2f_(e3 * narg);       \
            phi = fminf(fmaxf(phi, 1e-30f), 1e6f);                              \
            float cp   = fminf((float)(zi * zj), 1e4f);                         \
            float brep = fminf(0.5f * cp * rsq, 1e6f);                          \
            float r    = brep * phi * fmaxf(sw, 1e-30f);                        \
            r = fminf(fmaxf(r, 0.0f), 1e6f);                                    \
            if (!(r == r)) r = 0.0f;                                            \
            rep = r * (g).bm;                                                   \
            key = (g).ii;                                                       \
        }                                                                       \
    }

    // per-thread fire-and-forget deposit (no cross-lane reduction at all)
#define DEPOSIT_G(rep, key)                                                     \
    {                                                                           \
        if ((key) >= 0) {                                                       \
            int slot = (key) - kbase;                                           \
            if (slot < CAP) atomicAdd(&s_acc[slot], (rep));                     \
            else            atomicAdd(&out_acc[key], (rep));                    \
        }                                                                       \
    }

    // ---- depth-3 / unroll-2 pipeline (R13's proven main loop)
    G a0 = loadG(idx_i, idx_j, batch_mask, disp, cbeg + tid,              cend);
    G b0 = loadG(idx_i, idx_j, batch_mask, disp, cbeg + BLK + tid,        cend);
    G a1 = loadG(idx_i, idx_j, batch_mask, disp, cbeg + STRD + tid,       cend);
    G b1 = loadG(idx_i, idx_j, batch_mask, disp, cbeg + STRD + BLK + tid, cend);

    for (int pb = cbeg; pb < cend; pb += STRD) {
        G a2 = loadG(idx_i, idx_j, batch_mask, disp, pb + 2 * STRD + tid,       cend);
        G b2 = loadG(idx_i, idx_j, batch_mask, disp, pb + 2 * STRD + BLK + tid, cend);

        float repA, repB; int keyA, keyB;
        COMPUTE_G(a0, repA, keyA);
        COMPUTE_G(b0, repB, keyB);
        DEPOSIT_G(repA, keyA);
        DEPOSIT_G(repB, keyB);

        a0 = a1; b0 = b1; a1 = a2; b1 = b2;
    }
#undef COMPUTE_G
#undef DEPOSIT_G

    // ---- flush LDS slots to global (few hundred nonzero per block)
    __syncthreads();
    for (int s = tid; s < CAP; s += BLK) {
        float v = s_acc[s];
        int   k = kbase + s;
        if (v != 0.0f && k < nA) atomicAdd(&out_acc[k], v);
    }
}

__global__ void zbl_epilogue(float* __restrict__ out,
                             const float* __restrict__ atom_mask, int n) {
    int i = blockIdx.x * blockDim.x + threadIdx.x;
    if (i >= n) return;
    float v = out[i] * atom_mask[i];
    v = fminf(fmaxf(v, 0.0f), 1e6f);
    if (!(v == v)) v = 0.0f;
    out[i] = v * 0.01f;
}

extern "C" void kernel_launch(void* const* d_in, const int* in_sizes, int n_in,
                              void* d_out, int out_size, void* d_ws, size_t ws_size,
                              hipStream_t stream) {
    const float* an         = (const float*)d_in[0];
    const float* disp       = (const float*)d_in[1];
    const int*   idx_i      = (const int*)d_in[2];
    const int*   idx_j      = (const int*)d_in[3];
    const float* atom_mask  = (const float*)d_in[4];
    const float* batch_mask = (const float*)d_in[5];
    const float* a_coef     = (const float*)d_in[8];
    const float* a_exp      = (const float*)d_in[9];
    const float* phi_c      = (const float*)d_in[10];
    const float* phi_e      = (const float*)d_in[11];

    const int nA = in_sizes[0];
    const int nP = in_sizes[2];
    float* out = (float*)d_out;

    unsigned char* z8 = (unsigned char*)d_ws;   // 100 KB, ws ample

    zbl_k0<<<(nA + 255) / 256, 256, 0, stream>>>(an, z8, out, nA);

    const int nA_pad = (nA + 15) & ~15;
    const size_t smem = (size_t)nA_pad + 1024 + (size_t)CAP * sizeof(float);
    zbl_pair_kernel<<<NBLK, BLK, smem, stream>>>(
        disp, idx_i, idx_j, batch_mask, z8, a_coef, a_exp, phi_c, phi_e,
        out, nA, nP);

    zbl_epilogue<<<(nA + 255) / 256, 256, 0, stream>>>(out, atom_mask, nA);
}

// Round 16
// 44.863 us; speedup vs baseline: 1.6126x; 1.6126x over previous
//
#include <hip/hip_runtime.h>
#include <math.h>

// ---------------------------------------------------------------------------
// ZBL repulsion, R16: R13 skeleton + 4 pairs/thread vector loads.
//  - per 256 pairs: 6 VMEM instrs (int4,int4,float4,3xfloat4) vs R13's 16,
//    and ONE segmented scan vs 4 (scan was the dominant serial chain)
//  - local run-merge of the 4 consecutive sorted keys; internal run
//    boundaries (~5% of threads) deposit directly to the LDS slot
//  - 1024-thr persistent blocks, LDS z8 (100 KB) + za[256] + slots (CAP)
//  - depth-3 register pipeline, barrier-free main loop
//  - R13's flush + epilogue; native exp2/rcp/rsq math (absmax 2.4e-4 ok)
// ---------------------------------------------------------------------------

#define LOG2E 1.4426950408889634f
#define BLK   1024
#define NBLK  256
#define PPT   4
#define STRD  (BLK * PPT)
#define CAP   2048

static __device__ __forceinline__ float rcpf_(float x)  { return __builtin_amdgcn_rcpf(x); }
static __device__ __forceinline__ float rsqf_(float x)  { return __builtin_amdgcn_rsqf(x); }
static __device__ __forceinline__ float exp2f_(float x) { return __builtin_amdgcn_exp2f(x); }
static __device__ __forceinline__ float log2f_(float x) { return __builtin_amdgcn_logf(x); }

struct G4 { int ii0,ii1,ii2,ii3, jj0,jj1,jj2,jj3;
            float bm0,bm1,bm2,bm3;
            float dx0,dx1,dx2,dx3, dy0,dy1,dy2,dy3, dz0,dz1,dz2,dz3; };

__global__ void zbl_k0(const float* __restrict__ an,
                       unsigned char* __restrict__ z8,
                       float* __restrict__ out, int n) {
    int i = blockIdx.x * blockDim.x + threadIdx.x;
    if (i >= n) return;
    int z = (int)(an[i] + 0.5f);
    z8[i] = (unsigned char)min(max(z, 1), 255);
    out[i] = 0.0f;
}

static __device__ __forceinline__ G4 loadG4(const int* __restrict__ idx_i,
                                            const int* __restrict__ idx_j,
                                            const float* __restrict__ bmk,
                                            const float* __restrict__ disp,
                                            int p0, int cend) {
    G4 g;
    if (p0 + PPT <= cend) {
        const int4   ii = *reinterpret_cast<const int4*>(idx_i + p0);
        const int4   jj = *reinterpret_cast<const int4*>(idx_j + p0);
        const float4 bm = *reinterpret_cast<const float4*>(bmk + p0);
        const float4* d4 = reinterpret_cast<const float4*>(disp + (long)p0 * 3);
        const float4 d0 = d4[0], d1 = d4[1], d2 = d4[2];
        g.ii0=ii.x; g.ii1=ii.y; g.ii2=ii.z; g.ii3=ii.w;
        g.jj0=jj.x; g.jj1=jj.y; g.jj2=jj.z; g.jj3=jj.w;
        g.bm0=bm.x; g.bm1=bm.y; g.bm2=bm.z; g.bm3=bm.w;
        g.dx0=d0.x; g.dy0=d0.y; g.dz0=d0.z;
        g.dx1=d0.w; g.dy1=d1.x; g.dz1=d1.y;
        g.dx2=d1.z; g.dy2=d1.w; g.dz2=d2.x;
        g.dx3=d2.y; g.dy3=d2.z; g.dz3=d2.w;
    } else {
        int   ii[4], jj[4]; float bm[4], dx[4], dy[4], dz[4];
        #pragma unroll
        for (int k = 0; k < PPT; ++k) {
            const int p = p0 + k;
            if (p < cend) {
                ii[k] = idx_i[p]; jj[k] = idx_j[p]; bm[k] = bmk[p];
                const float* dp = disp + (long)p * 3;
                dx[k] = dp[0]; dy[k] = dp[1]; dz[k] = dp[2];
            } else { ii[k] = -1; jj[k] = 0; bm[k] = 0.f; dx[k]=dy[k]=dz[k]=0.f; }
        }
        g.ii0=ii[0]; g.ii1=ii[1]; g.ii2=ii[2]; g.ii3=ii[3];
        g.jj0=jj[0]; g.jj1=jj[1]; g.jj2=jj[2]; g.jj3=jj[3];
        g.bm0=bm[0]; g.bm1=bm[1]; g.bm2=bm[2]; g.bm3=bm[3];
        g.dx0=dx[0]; g.dx1=dx[1]; g.dx2=dx[2]; g.dx3=dx[3];
        g.dy0=dy[0]; g.dy1=dy[1]; g.dy2=dy[2]; g.dy3=dy[3];
        g.dz0=dz[0]; g.dz1=dz[1]; g.dz2=dz[2]; g.dz3=dz[3];
    }
    return g;
}

__global__ __launch_bounds__(BLK) void zbl_pair_kernel(
    const float* __restrict__ disp,
    const int*   __restrict__ idx_i,       // sorted
    const int*   __restrict__ idx_j,
    const float* __restrict__ batch_mask,
    const unsigned char* __restrict__ z8g,
    const float* __restrict__ a_coef_ptr,
    const float* __restrict__ a_exp_ptr,
    const float* __restrict__ phi_c,
    const float* __restrict__ phi_e,
    float* __restrict__ out_acc,           // [N] zeroed accumulator
    int nA, int nP)
{
    extern __shared__ unsigned char smem[];
    const int nA_pad = (nA + 15) & ~15;
    unsigned char* s_z8  = smem;
    float*         s_za  = (float*)(smem + nA_pad);
    float*         s_acc = (float*)(smem + nA_pad + 1024);

    const int tid = threadIdx.x;

    {
        const int nw = nA >> 4;
        const uint4* g4 = reinterpret_cast<const uint4*>(z8g);
        uint4* s4 = reinterpret_cast<uint4*>(s_z8);
        for (int i = tid; i < nw; i += BLK) s4[i] = g4[i];
        for (int i = (nw << 4) + tid; i < nA; i += BLK) s_z8[i] = z8g[i];
    }
    if (tid < 256) {
        float ae = fabsf(a_exp_ptr[0]);
        int z = max(tid, 1);
        s_za[tid] = exp2f_(ae * log2f_((float)z));
    }
    for (int i = tid; i < CAP; i += BLK) s_acc[i] = 0.0f;

    const float ac_inv = rcpf_(fmaxf(fabsf(a_coef_ptr[0]), 1e-10f));
    float c0 = fabsf(phi_c[0]), c1 = fabsf(phi_c[1]);
    float c2 = fabsf(phi_c[2]), c3 = fabsf(phi_c[3]);
    const float cinv = rcpf_(fmaxf(c0 + c1 + c2 + c3, 1e-10f));
    c0 *= cinv; c1 *= cinv; c2 *= cinv; c3 *= cinv;
    const float e0 = fmaxf(fabsf(phi_e[0]), 1e-10f);
    const float e1 = fmaxf(fabsf(phi_e[1]), 1e-10f);
    const float e2 = fmaxf(fabsf(phi_e[2]), 1e-10f);
    const float e3 = fmaxf(fabsf(phi_e[3]), 1e-10f);

    int chunk = (nP + NBLK - 1) / NBLK;
    chunk = (chunk + PPT - 1) & ~(PPT - 1);      // keep int4/float4 alignment
    const int cbeg = min(blockIdx.x * chunk, nP);
    const int cend = min(cbeg + chunk, nP);
    const int lane = tid & 63;
    const int kbase = (cbeg < nP) ? idx_i[cbeg] : 0;

    __syncthreads();

#define PAIR_REP(II, JJ, BM, DX, DY, DZ, rep)                                   \
    {                                                                           \
        rep = 0.0f;                                                             \
        if ((II) >= 0) {                                                        \
            const int zi = (int)s_z8[(II)];                                     \
            const int zj = (int)s_z8[(JJ)];                                     \
            const float za_i = s_za[zi];                                        \
            const float za_j = s_za[zj];                                        \
            const float add = 1.0f - (BM);                                      \
            const float dx = (DX) + add, dy = (DY) + add, dz = (DZ) + add;      \
            float d2   = fmaxf(dx * dx + dy * dy + dz * dz, 1e-20f);            \
            float rsq  = rsqf_(d2);                                             \
            float dist = d2 * rsq;                                              \
            float tt = dist * 0.1f;                                             \
            float tc = fminf(fmaxf(tt, 1e-9f), 1.0f - 1e-9f);                   \
            float u  = (1.0f - 2.0f * tc) * rcpf_(tc - tc * tc);                \
            float s  = rcpf_(1.0f + exp2f_(u * LOG2E));                         \
            float sw = (tt >= 1.0f) ? 1.0f : s;                                 \
            float za_sum = za_i + za_j;                                         \
            float arg  = fminf(dist * za_sum * ac_inv, 1e6f);                   \
            float narg = -arg * LOG2E;                                          \
            float phi  = c0 * exp2f_(e0 * narg) + c1 * exp2f_(e1 * narg) +      \
                         c2 * exp2f_(e2 * narg) + c3 * exp2f_(e3 * narg);       \
            phi = fminf(fmaxf(phi, 1e-30f), 1e6f);                              \
            float cp   = fminf((float)(zi * zj), 1e4f);                         \
            float brep = fminf(0.5f * cp * rsq, 1e6f);                          \
            float r    = brep * phi * fmaxf(sw, 1e-30f);                        \
            r = fminf(fmaxf(r, 0.0f), 1e6f);                                    \
            if (!(r == r)) r = 0.0f;                                            \
            rep = r * (BM);                                                     \
        }                                                                       \
    }

#define DEPOSIT(k, v)                                                           \
    {                                                                           \
        if ((k) >= 0) {                                                         \
            int slot = (k) - kbase;                                             \
            if (slot < CAP) atomicAdd(&s_acc[slot], (v));                       \
            else            atomicAdd(&out_acc[k], (v));                        \
        }                                                                       \
    }

#define MERGE(K, R)                                                             \
    {                                                                           \
        if ((K) == runkey) runsum += (R);                                       \
        else { DEPOSIT(runkey, runsum); runkey = (K); runsum = (R); }           \
    }

    // ---- depth-3 pipeline over 4-pair windows
    G4 s0 = loadG4(idx_i, idx_j, batch_mask, disp, cbeg + tid * PPT,            cend);
    G4 s1 = loadG4(idx_i, idx_j, batch_mask, disp, cbeg + STRD + tid * PPT,     cend);

    for (int pb = cbeg; pb < cend; pb += STRD) {
        G4 s2 = loadG4(idx_i, idx_j, batch_mask, disp,
                       pb + 2 * STRD + tid * PPT, cend);

        // compute 4 pairs
        float r0, r1, r2, r3;
        PAIR_REP(s0.ii0, s0.jj0, s0.bm0, s0.dx0, s0.dy0, s0.dz0, r0);
        PAIR_REP(s0.ii1, s0.jj1, s0.bm1, s0.dx1, s0.dy1, s0.dz1, r1);
        PAIR_REP(s0.ii2, s0.jj2, s0.bm2, s0.dx2, s0.dy2, s0.dz2, r2);
        PAIR_REP(s0.ii3, s0.jj3, s0.bm3, s0.dx3, s0.dy3, s0.dz3, r3);

        // local run-merge (sorted keys; internal boundaries are rare)
        int   runkey = s0.ii0;
        float runsum = r0;
        MERGE(s0.ii1, r1);
        MERGE(s0.ii2, r2);
        MERGE(s0.ii3, r3);

        // ONE wave segmented scan per 4096-pair block step
        {
            const int k0_ = __shfl(runkey, 0);
            if (__all(runkey == k0_)) {
                float v = runsum;
                #pragma unroll
                for (int d = 1; d < 64; d <<= 1) v += __shfl_xor(v, d);
                if (lane == 0) DEPOSIT(k0_, v);
            } else {
                float v = runsum;
                int   k = runkey;
                #pragma unroll
                for (int d = 1; d < 64; d <<= 1) {
                    float nv = __shfl_down(v, d);
                    int   nk = __shfl_down(k, d);
                    if (lane + d < 64 && nk == k) v += nv;
                }
                int pk = __shfl_up(k, 1);
                bool head = (lane == 0) || (pk != k);
                if (head) DEPOSIT(k, v);
            }
        }

        s0 = s1; s1 = s2;
    }
#undef PAIR_REP
#undef DEPOSIT
#undef MERGE

    // ---- flush LDS slots to global
    __syncthreads();
    for (int s = tid; s < CAP; s += BLK) {
        float v = s_acc[s];
        int   k = kbase + s;
        if (v != 0.0f && k < nA) atomicAdd(&out_acc[k], v);
    }
}

__global__ void zbl_epilogue(float* __restrict__ out,
                             const float* __restrict__ atom_mask, int n) {
    int i = blockIdx.x * blockDim.x + threadIdx.x;
    if (i >= n) return;
    float v = out[i] * atom_mask[i];
    v = fminf(fmaxf(v, 0.0f), 1e6f);
    if (!(v == v)) v = 0.0f;
    out[i] = v * 0.01f;
}

extern "C" void kernel_launch(void* const* d_in, const int* in_sizes, int n_in,
                              void* d_out, int out_size, void* d_ws, size_t ws_size,
                              hipStream_t stream) {
    const float* an         = (const float*)d_in[0];
    const float* disp       = (const float*)d_in[1];
    const int*   idx_i      = (const int*)d_in[2];
    const int*   idx_j      = (const int*)d_in[3];
    const float* atom_mask  = (const float*)d_in[4];
    const float* batch_mask = (const float*)d_in[5];
    const float* a_coef     = (const float*)d_in[8];
    const float* a_exp      = (const float*)d_in[9];
    const float* phi_c      = (const float*)d_in[10];
    const float* phi_e      = (const float*)d_in[11];

    const int nA = in_sizes[0];
    const int nP = in_sizes[2];
    float* out = (float*)d_out;

    unsigned char* z8 = (unsigned char*)d_ws;

    zbl_k0<<<(nA + 255) / 256, 256, 0, stream>>>(an, z8, out, nA);

    const int nA_pad = (nA + 15) & ~15;
    const size_t smem = (size_t)nA_pad + 1024 + (size_t)CAP * sizeof(float);
    zbl_pair_kernel<<<NBLK, BLK, smem, stream>>>(
        disp, idx_i, idx_j, batch_mask, z8, a_coef, a_exp, phi_c, phi_e,
        out, nA, nP);

    zbl_epilogue<<<(nA + 255) / 256, 256, 0, stream>>>(out, atom_mask, nA);
}